// Round 5
// baseline (2168.101 us; speedup 1.0000x reference)
//
#include <hip/hip_runtime.h>

#define BB 128
#define NN 512
#define HH 128
#define TT 4

// ---------------- correctness-anchor round: pure fp32, reference-faithful ----------------
// h state lives in d_out ([B,N,H] fp32 == the required output after T steps).
// ws: wT (6 transposed 128x128 weight mats, 384 KB) + a32 ([B,N,H] fp32, 33.5 MB).

// transpose the six HxH weights so gate k-loops read coalesced columns:
// wT[mat][k*128 + j] = W[mat][j*128 + k]
__global__ void k_wT(const float* __restrict__ wz, const float* __restrict__ uz,
                     const float* __restrict__ wr, const float* __restrict__ ur,
                     const float* __restrict__ wc, const float* __restrict__ uc,
                     float* __restrict__ wT) {
  int mat = blockIdx.x >> 6;
  int o = ((blockIdx.x & 63) << 8) + threadIdx.x;   // o = k*128 + j
  int k = o >> 7, j = o & 127;
  const float* src = mat==0?wz : mat==1?uz : mat==2?wr : mat==3?ur : mat==4?wc : uc;
  wT[mat*16384 + o] = src[j*HH + k];
}

__global__ void k_copy_h0(const float* __restrict__ hin, float* __restrict__ h) {
  int v = blockIdx.x * 256 + threadIdx.x;
  ((float4*)h)[v] = ((const float4*)hin)[v];
}

// a32[b][n][j] = b_ah[j] + sum_m A[b][m][n] * h[b][m][j]
// block = (n-group of 8, batch b), 128 threads (j). A-tile staged in LDS,
// broadcast-read; h read coalesced once per (m, n-group).
__global__ __launch_bounds__(128) void k_a(const float* __restrict__ A,
                                           const float* __restrict__ h,
                                           const float* __restrict__ b_ah,
                                           float* __restrict__ a32) {
  __shared__ float At[32][8];
  const int b = blockIdx.y, n0 = blockIdx.x * 8, j = threadIdx.x;
  const float* Ab = A + (size_t)b * NN * NN;
  const float* hb = h + (size_t)b * NN * HH;
  float acc[8];
  const float bah = b_ah[j];
#pragma unroll
  for (int i = 0; i < 8; i++) acc[i] = 0.f;
  for (int m0 = 0; m0 < NN; m0 += 32) {
#pragma unroll
    for (int i = 0; i < 2; i++) {
      int idx = j + i*128;                 // [0,256)
      int mm = idx >> 3, nn = idx & 7;
      At[mm][nn] = Ab[(size_t)(m0+mm)*NN + n0 + nn];
    }
    __syncthreads();
    for (int mm = 0; mm < 32; mm++) {
      float hv = hb[(size_t)(m0+mm)*HH + j];
#pragma unroll
      for (int i = 0; i < 8; i++) acc[i] += At[mm][i] * hv;
    }
    __syncthreads();
  }
  float* ab = a32 + (size_t)b * NN * HH;
#pragma unroll
  for (int i = 0; i < 8; i++) ab[(size_t)(n0+i)*HH + j] = acc[i] + bah;
}

// gates for 8 rows of [B*N]: straight from the reference formulas.
__global__ __launch_bounds__(128) void k_gates(const float* __restrict__ a32,
                                               float* __restrict__ h,
                                               const float* __restrict__ wT,
                                               const float* __restrict__ bwz, const float* __restrict__ buz,
                                               const float* __restrict__ bwr, const float* __restrict__ bur,
                                               const float* __restrict__ bw,  const float* __restrict__ bu) {
  __shared__ float ar[8][128], hr[8][128], rh[8][128];
  const int r0 = blockIdx.x * 8, j = threadIdx.x;
#pragma unroll
  for (int i = 0; i < 8; i++) {
    ar[i][j] = a32[(size_t)(r0+i)*HH + j];
    hr[i][j] = h[(size_t)(r0+i)*HH + j];
  }
  __syncthreads();
  const float* wTz = wT;
  const float* uTz = wT + 16384;
  const float* wTr = wT + 2*16384;
  const float* uTr = wT + 3*16384;
  const float* wTc = wT + 4*16384;
  const float* uTc = wT + 5*16384;
  const float bz = bwz[j] + buz[j], br = bwr[j] + bur[j], bc = bw[j] + bu[j];
  float pz[8], pr[8];
#pragma unroll
  for (int i = 0; i < 8; i++) { pz[i] = bz; pr[i] = br; }
  for (int k = 0; k < HH; k++) {
    float wzk = wTz[k*HH + j], uzk = uTz[k*HH + j];
    float wrk = wTr[k*HH + j], urk = uTr[k*HH + j];
#pragma unroll
    for (int i = 0; i < 8; i++) {
      pz[i] += ar[i][k]*wzk + hr[i][k]*uzk;
      pr[i] += ar[i][k]*wrk + hr[i][k]*urk;
    }
  }
  float zv[8];
#pragma unroll
  for (int i = 0; i < 8; i++) {
    zv[i] = 1.f / (1.f + expf(-pz[i]));
    float rv = 1.f / (1.f + expf(-pr[i]));
    rh[i][j] = rv * hr[i][j];
  }
  __syncthreads();
  float pc[8];
#pragma unroll
  for (int i = 0; i < 8; i++) pc[i] = bc;
  for (int k = 0; k < HH; k++) {
    float wck = wTc[k*HH + j], uck = uTc[k*HH + j];
#pragma unroll
    for (int i = 0; i < 8; i++)
      pc[i] += ar[i][k]*wck + rh[i][k]*uck;
  }
#pragma unroll
  for (int i = 0; i < 8; i++) {
    float cv = tanhf(pc[i]);
    float hv = hr[i][j];
    h[(size_t)(r0+i)*HH + j] = hv + zv[i]*(cv - hv);   // (1-z)h + z*c
  }
}

extern "C" void kernel_launch(void* const* d_in, const int* in_sizes, int n_in,
                              void* d_out, int out_size, void* d_ws, size_t ws_size,
                              hipStream_t stream) {
  const float* A      = (const float*)d_in[0];
  const float* hidden = (const float*)d_in[1];
  const float* b_ah   = (const float*)d_in[2];
  const float* w_z = (const float*)d_in[3];  const float* b_wz = (const float*)d_in[4];
  const float* u_z = (const float*)d_in[5];  const float* b_uz = (const float*)d_in[6];
  const float* w_r = (const float*)d_in[7];  const float* b_wr = (const float*)d_in[8];
  const float* u_r = (const float*)d_in[9];  const float* b_ur = (const float*)d_in[10];
  const float* w   = (const float*)d_in[11]; const float* b_w  = (const float*)d_in[12];
  const float* u   = (const float*)d_in[13]; const float* b_u  = (const float*)d_in[14];

  float* h = (float*)d_out;                       // fp32 h state == output [B,N,H]
  char* ws = (char*)d_ws;
  float* wT  = (float*)ws;                        // 393,216 B
  float* a32 = (float*)(ws + 393216);             // 33,554,432 B  (total ws ~34 MB)

  k_wT<<<384, 256, 0, stream>>>(w_z, u_z, w_r, u_r, w, u, wT);
  k_copy_h0<<<8192, 256, 0, stream>>>(hidden, h);

  for (int t = 0; t < TT; t++) {
    k_a<<<dim3(64, BB), 128, 0, stream>>>(A, h, b_ah, a32);
    k_gates<<<8192, 128, 0, stream>>>(a32, h, wT, b_wz, b_uz, b_wr, b_ur, b_w, b_u);
  }
}

// Round 6
// 1014.258 us; speedup vs baseline: 2.1376x; 2.1376x over previous
//
#include <hip/hip_runtime.h>
#include <hip/hip_fp16.h>

#define BB 128
#define NN 512
#define HH 128
#define TT 4

typedef _Float16 f16;
typedef _Float16 half8 __attribute__((ext_vector_type(8)));
typedef float floatx4 __attribute__((ext_vector_type(4)));

// fp32 -> f16 hi/lo split: x ~= hi + lo, |lo| <= |x|*2^-11
__device__ __forceinline__ void split1(float x, f16& hi, f16& lo) {
  hi = (f16)x;
  lo = (f16)(x - (float)hi);
}

// ---------- one-time prep ----------

// six HxH fp32 weights, pre-scaled x16, split into f16 hi/lo
__global__ void k_wsplit(const float* __restrict__ wz, const float* __restrict__ uz,
                         const float* __restrict__ wr, const float* __restrict__ ur,
                         const float* __restrict__ wc, const float* __restrict__ uc,
                         f16* __restrict__ whi, f16* __restrict__ wlo) {
  int mat = blockIdx.x >> 6;
  int idx = ((blockIdx.x & 63) << 8) + threadIdx.x;
  const float* src = mat==0?wz : mat==1?uz : mat==2?wr : mat==3?ur : mat==4?wc : uc;
  float v = src[idx] * 16.0f;
  f16 hi, lo; split1(v, hi, lo);
  whi[mat*16384 + idx] = hi;
  wlo[mat*16384 + idx] = lo;
}

// summed gate biases: [0]=b_wz+b_uz, [1]=b_wr+b_ur, [2]=b_w+b_u
__global__ void k_bsum(const float* __restrict__ bwz, const float* __restrict__ buz,
                       const float* __restrict__ bwr, const float* __restrict__ bur,
                       const float* __restrict__ bw,  const float* __restrict__ bu,
                       float* __restrict__ bias3) {
  int b = blockIdx.x, j = threadIdx.x;
  bias3[b*HH + j] = b==0 ? bwz[j]+buz[j] : (b==1 ? bwr[j]+bur[j] : bw[j]+bu[j]);
}

__global__ void k_copy_h0(const float* __restrict__ hin, float* __restrict__ h) {
  int v = blockIdx.x * 256 + threadIdx.x;
  ((float4*)h)[v] = ((const float4*)hin)[v];
}

// ---------- per-step kernels ----------

// a32[b][n][j] = b_ah[j] + sum_m A[b][m][n] * h[b][m][j], fp32-accurate via
// hi/lo split f16 MFMA (3 passes). In-kernel transpose staging, XOR-swizzled.
// grid (4 n-tiles, 128 batch), 256 thr (4 waves), tile 128x128, BK=64.
__global__ __launch_bounds__(256) void k_biggemm(const float* __restrict__ A,
                                                 const float* __restrict__ h,
                                                 const float* __restrict__ b_ah,
                                                 float* __restrict__ a32) {
  __shared__ __align__(16) f16 Ah[128*64], Al[128*64], Hh[128*64], Hl[128*64];
  const int b = blockIdx.y, n0 = blockIdx.x * 128, tid = threadIdx.x;
  const int w = tid >> 6, L = tid & 63, quad = L >> 4, l16 = L & 15;
  const int rowsel = tid >> 5, colsel = tid & 31;
  const float* Ab = A + (size_t)b * NN * NN;
  const float* hb = h + (size_t)b * NN * HH;
  const floatx4 zero = {0.f, 0.f, 0.f, 0.f};
  floatx4 acc[2][8];
  for (int sr = 0; sr < 2; sr++) for (int sc = 0; sc < 8; sc++) acc[sr][sc] = zero;

  for (int mc = 0; mc < NN; mc += 64) {
    float4 va[8], vh[8];
#pragma unroll
    for (int i = 0; i < 8; i++) {
      int mm = rowsel * 8 + i;
      va[i] = *(const float4*)(Ab + (size_t)(mc + mm) * NN + n0 + colsel * 4);
      vh[i] = *(const float4*)(hb + (size_t)(mc + mm) * HH + colsel * 4);
    }
#pragma unroll
    for (int q = 0; q < 4; q++) {
      int c = colsel * 4 + q;
      half8 avh, avl, hvh, hvl;
#pragma unroll
      for (int i = 0; i < 8; i++) {
        f16 hi, lo;
        split1(((const float*)&va[i])[q], hi, lo); avh[i] = hi; avl[i] = lo;
        split1(((const float*)&vh[i])[q], hi, lo); hvh[i] = hi; hvl[i] = lo;
      }
      int blk = (rowsel ^ (c & 7)) * 8;
      *(half8*)&Ah[c*64 + blk] = avh;  *(half8*)&Al[c*64 + blk] = avl;
      *(half8*)&Hh[c*64 + blk] = hvh;  *(half8*)&Hl[c*64 + blk] = hvl;
    }
    __syncthreads();
#pragma unroll
    for (int ks = 0; ks < 2; ks++) {
      const int kb = ks * 4 + quad;
      half8 afh[2], afl[2], bfh[8], bfl[8];
      for (int sr = 0; sr < 2; sr++) {
        int c = w*32 + sr*16 + l16, o = c*64 + ((kb ^ (c & 7)) * 8);
        afh[sr] = *(const half8*)&Ah[o];
        afl[sr] = *(const half8*)&Al[o];
      }
      for (int sc = 0; sc < 8; sc++) {
        int c = sc*16 + l16, o = c*64 + ((kb ^ (c & 7)) * 8);
        bfh[sc] = *(const half8*)&Hh[o];
        bfl[sc] = *(const half8*)&Hl[o];
      }
      for (int sr = 0; sr < 2; sr++)
        for (int sc = 0; sc < 8; sc++) {
          acc[sr][sc] = __builtin_amdgcn_mfma_f32_16x16x32_f16(afh[sr], bfh[sc], acc[sr][sc], 0, 0, 0);
          acc[sr][sc] = __builtin_amdgcn_mfma_f32_16x16x32_f16(afh[sr], bfl[sc], acc[sr][sc], 0, 0, 0);
          acc[sr][sc] = __builtin_amdgcn_mfma_f32_16x16x32_f16(afl[sr], bfh[sc], acc[sr][sc], 0, 0, 0);
        }
    }
    __syncthreads();
  }
  float bah[8];
  for (int sc = 0; sc < 8; sc++) bah[sc] = b_ah[sc*16 + l16];
  float* ab = a32 + (size_t)b * NN * HH;
#pragma unroll
  for (int sr = 0; sr < 2; sr++)
    for (int rg = 0; rg < 4; rg++) {
      const int row = n0 + w*32 + sr*16 + quad*4 + rg;   // C/D: row=quad*4+reg
      for (int sc = 0; sc < 8; sc++)
        ab[(size_t)row*HH + sc*16 + l16] = acc[sr][sc][rg] + bah[sc];  // col=lane&15
    }
}

// gates, 128 rows of [B*N] per block. All GEMMs hi/lo-split f16 MFMA (3 passes),
// weights pre-scaled x16 (epilogue /16). h fp32 in d_out; a fp32 in ws.
// Sweeps: r -> (rh to LDS hi/lo) -> c -> z -> h update.
__global__ __launch_bounds__(256) void k_gates(const float* __restrict__ a32,
                                               float* __restrict__ h,
                                               const f16* __restrict__ whi,
                                               const f16* __restrict__ wlo,
                                               const float* __restrict__ bias3) {
  __shared__ __align__(16) f16 rhh[128*136], rhl[128*136];
  const int row0 = blockIdx.x << 7, tid = threadIdx.x;
  const int w = tid >> 6, L = tid & 63, quad = L >> 4, l16 = L & 15;
  const float* ap[2]; const float* hp[2];
  for (int sr = 0; sr < 2; sr++) {
    int r = row0 + w*32 + sr*16 + l16;
    ap[sr] = a32 + (size_t)r * HH;
    hp[sr] = h + (size_t)r * HH;
  }
  // a fragments (live across all sweeps): A-op layout m=lane&15, k=quad*8+j
  half8 afh[2][4], afl[2][4];
#pragma unroll
  for (int sr = 0; sr < 2; sr++)
#pragma unroll
    for (int ks = 0; ks < 4; ks++) {
      const int ko = ks*32 + quad*8;
      float4 p = *(const float4*)(ap[sr] + ko);
      float4 q2 = *(const float4*)(ap[sr] + ko + 4);
      const float* v = (const float*)&p;
      const float* v2 = (const float*)&q2;
      for (int i = 0; i < 4; i++) { f16 hi, lo; split1(v[i],  hi, lo); afh[sr][ks][i]   = hi; afl[sr][ks][i]   = lo; }
      for (int i = 0; i < 4; i++) { f16 hi, lo; split1(v2[i], hi, lo); afh[sr][ks][i+4] = hi; afl[sr][ks][i+4] = lo; }
    }
  const floatx4 zero = {0.f, 0.f, 0.f, 0.f};
  const f16* Wz_h = whi;            const f16* Wz_l = wlo;
  const f16* Uz_h = whi + 16384;    const f16* Uz_l = wlo + 16384;
  const f16* Wr_h = whi + 2*16384;  const f16* Wr_l = wlo + 2*16384;
  const f16* Ur_h = whi + 3*16384;  const f16* Ur_l = wlo + 3*16384;
  const f16* Wc_h = whi + 4*16384;  const f16* Wc_l = wlo + 4*16384;
  const f16* Uc_h = whi + 5*16384;  const f16* Uc_l = wlo + 5*16384;

  // ---- r sweep ----
  floatx4 racc[2][8];
  for (int sr = 0; sr < 2; sr++) for (int sc = 0; sc < 8; sc++) racc[sr][sc] = zero;
#pragma unroll
  for (int ks = 0; ks < 4; ks++) {
    const int ko = ks*32 + quad*8;
    half8 hfh[2], hfl[2];
    for (int sr = 0; sr < 2; sr++) {
      float4 p = *(const float4*)(hp[sr] + ko);
      float4 q2 = *(const float4*)(hp[sr] + ko + 4);
      const float* v = (const float*)&p; const float* v2 = (const float*)&q2;
      for (int i = 0; i < 4; i++) { f16 hi, lo; split1(v[i],  hi, lo); hfh[sr][i]   = hi; hfl[sr][i]   = lo; }
      for (int i = 0; i < 4; i++) { f16 hi, lo; split1(v2[i], hi, lo); hfh[sr][i+4] = hi; hfl[sr][i+4] = lo; }
    }
#pragma unroll
    for (int sc = 0; sc < 8; sc++) {
      const int wo = (sc*16 + l16)*HH + ko;      // B-op: n=lane&15 row of W, k-contig
      half8 wh = *(const half8*)(Wr_h + wo), wl = *(const half8*)(Wr_l + wo);
      half8 uh = *(const half8*)(Ur_h + wo), ul = *(const half8*)(Ur_l + wo);
      for (int sr = 0; sr < 2; sr++) {
        racc[sr][sc] = __builtin_amdgcn_mfma_f32_16x16x32_f16(afh[sr][ks], wh, racc[sr][sc], 0, 0, 0);
        racc[sr][sc] = __builtin_amdgcn_mfma_f32_16x16x32_f16(afh[sr][ks], wl, racc[sr][sc], 0, 0, 0);
        racc[sr][sc] = __builtin_amdgcn_mfma_f32_16x16x32_f16(afl[sr][ks], wh, racc[sr][sc], 0, 0, 0);
        racc[sr][sc] = __builtin_amdgcn_mfma_f32_16x16x32_f16(hfh[sr], uh, racc[sr][sc], 0, 0, 0);
        racc[sr][sc] = __builtin_amdgcn_mfma_f32_16x16x32_f16(hfh[sr], ul, racc[sr][sc], 0, 0, 0);
        racc[sr][sc] = __builtin_amdgcn_mfma_f32_16x16x32_f16(hfl[sr], uh, racc[sr][sc], 0, 0, 0);
      }
    }
  }
  // epilogue r: rh = sigmoid(pr)*h -> LDS (C/D row=quad*4+reg, col=lane&15)
  {
    float brv[8];
    for (int sc = 0; sc < 8; sc++) brv[sc] = bias3[128 + sc*16 + l16];
#pragma unroll
    for (int sr = 0; sr < 2; sr++)
#pragma unroll
      for (int rg = 0; rg < 4; rg++) {
        const int lrow = w*32 + sr*16 + quad*4 + rg;
        const float* hrow = h + (size_t)(row0 + lrow)*HH;
        for (int sc = 0; sc < 8; sc++) {
          const int col = sc*16 + l16;
          float pr = racc[sr][sc][rg] * 0.0625f + brv[sc];
          float rv = 1.f / (1.f + expf(-pr));
          float rhv = rv * hrow[col];
          f16 hi, lo; split1(rhv, hi, lo);
          rhh[lrow*136 + col] = hi;
          rhl[lrow*136 + col] = lo;
        }
      }
  }
  __syncthreads();
  // ---- c sweep: a@Wc^T + rh@Uc^T ----
  floatx4 cacc[2][8];
  for (int sr = 0; sr < 2; sr++) for (int sc = 0; sc < 8; sc++) cacc[sr][sc] = zero;
#pragma unroll
  for (int ks = 0; ks < 4; ks++) {
    const int ko = ks*32 + quad*8;
    half8 rfh[2], rfl[2];
    for (int sr = 0; sr < 2; sr++) {
      int o = (w*32 + sr*16 + l16)*136 + ko;
      rfh[sr] = *(const half8*)&rhh[o];
      rfl[sr] = *(const half8*)&rhl[o];
    }
#pragma unroll
    for (int sc = 0; sc < 8; sc++) {
      const int wo = (sc*16 + l16)*HH + ko;
      half8 wh = *(const half8*)(Wc_h + wo), wl = *(const half8*)(Wc_l + wo);
      half8 uh = *(const half8*)(Uc_h + wo), ul = *(const half8*)(Uc_l + wo);
      for (int sr = 0; sr < 2; sr++) {
        cacc[sr][sc] = __builtin_amdgcn_mfma_f32_16x16x32_f16(afh[sr][ks], wh, cacc[sr][sc], 0, 0, 0);
        cacc[sr][sc] = __builtin_amdgcn_mfma_f32_16x16x32_f16(afh[sr][ks], wl, cacc[sr][sc], 0, 0, 0);
        cacc[sr][sc] = __builtin_amdgcn_mfma_f32_16x16x32_f16(afl[sr][ks], wh, cacc[sr][sc], 0, 0, 0);
        cacc[sr][sc] = __builtin_amdgcn_mfma_f32_16x16x32_f16(rfh[sr], uh, cacc[sr][sc], 0, 0, 0);
        cacc[sr][sc] = __builtin_amdgcn_mfma_f32_16x16x32_f16(rfh[sr], ul, cacc[sr][sc], 0, 0, 0);
        cacc[sr][sc] = __builtin_amdgcn_mfma_f32_16x16x32_f16(rfl[sr], uh, cacc[sr][sc], 0, 0, 0);
      }
    }
  }
  // ---- z sweep: a@Wz^T + h@Uz^T ----
  floatx4 zacc[2][8];
  for (int sr = 0; sr < 2; sr++) for (int sc = 0; sc < 8; sc++) zacc[sr][sc] = zero;
#pragma unroll
  for (int ks = 0; ks < 4; ks++) {
    const int ko = ks*32 + quad*8;
    half8 hfh[2], hfl[2];
    for (int sr = 0; sr < 2; sr++) {
      float4 p = *(const float4*)(hp[sr] + ko);
      float4 q2 = *(const float4*)(hp[sr] + ko + 4);
      const float* v = (const float*)&p; const float* v2 = (const float*)&q2;
      for (int i = 0; i < 4; i++) { f16 hi, lo; split1(v[i],  hi, lo); hfh[sr][i]   = hi; hfl[sr][i]   = lo; }
      for (int i = 0; i < 4; i++) { f16 hi, lo; split1(v2[i], hi, lo); hfh[sr][i+4] = hi; hfl[sr][i+4] = lo; }
    }
#pragma unroll
    for (int sc = 0; sc < 8; sc++) {
      const int wo = (sc*16 + l16)*HH + ko;
      half8 wh = *(const half8*)(Wz_h + wo), wl = *(const half8*)(Wz_l + wo);
      half8 uh = *(const half8*)(Uz_h + wo), ul = *(const half8*)(Uz_l + wo);
      for (int sr = 0; sr < 2; sr++) {
        zacc[sr][sc] = __builtin_amdgcn_mfma_f32_16x16x32_f16(afh[sr][ks], wh, zacc[sr][sc], 0, 0, 0);
        zacc[sr][sc] = __builtin_amdgcn_mfma_f32_16x16x32_f16(afh[sr][ks], wl, zacc[sr][sc], 0, 0, 0);
        zacc[sr][sc] = __builtin_amdgcn_mfma_f32_16x16x32_f16(afl[sr][ks], wh, zacc[sr][sc], 0, 0, 0);
        zacc[sr][sc] = __builtin_amdgcn_mfma_f32_16x16x32_f16(hfh[sr], uh, zacc[sr][sc], 0, 0, 0);
        zacc[sr][sc] = __builtin_amdgcn_mfma_f32_16x16x32_f16(hfh[sr], ul, zacc[sr][sc], 0, 0, 0);
        zacc[sr][sc] = __builtin_amdgcn_mfma_f32_16x16x32_f16(hfl[sr], uh, zacc[sr][sc], 0, 0, 0);
      }
    }
  }
  // ---- final epilogue ----
  float bzv[8], bcv[8];
  for (int sc = 0; sc < 8; sc++) {
    bzv[sc] = bias3[sc*16 + l16];
    bcv[sc] = bias3[256 + sc*16 + l16];
  }
#pragma unroll
  for (int sr = 0; sr < 2; sr++)
#pragma unroll
    for (int rg = 0; rg < 4; rg++) {
      const int lrow = w*32 + sr*16 + quad*4 + rg;
      float* hrow = h + (size_t)(row0 + lrow)*HH;
      for (int sc = 0; sc < 8; sc++) {
        const int col = sc*16 + l16;
        float pz = zacc[sr][sc][rg] * 0.0625f + bzv[sc];
        float zv = 1.f / (1.f + expf(-pz));
        float cv = tanhf(cacc[sr][sc][rg] * 0.0625f + bcv[sc]);
        float hv = hrow[col];
        hrow[col] = hv + zv*(cv - hv);   // (1-z)h + z*c
      }
    }
}

extern "C" void kernel_launch(void* const* d_in, const int* in_sizes, int n_in,
                              void* d_out, int out_size, void* d_ws, size_t ws_size,
                              hipStream_t stream) {
  const float* A      = (const float*)d_in[0];
  const float* hidden = (const float*)d_in[1];
  const float* b_ah   = (const float*)d_in[2];
  const float* w_z = (const float*)d_in[3];  const float* b_wz = (const float*)d_in[4];
  const float* u_z = (const float*)d_in[5];  const float* b_uz = (const float*)d_in[6];
  const float* w_r = (const float*)d_in[7];  const float* b_wr = (const float*)d_in[8];
  const float* u_r = (const float*)d_in[9];  const float* b_ur = (const float*)d_in[10];
  const float* w   = (const float*)d_in[11]; const float* b_w  = (const float*)d_in[12];
  const float* u   = (const float*)d_in[13]; const float* b_u  = (const float*)d_in[14];

  float* h = (float*)d_out;                       // fp32 h state == output [B,N,H]
  char* ws = (char*)d_ws;
  float* a32  = (float*)ws;                       // 33,554,432 B
  f16*   whi  = (f16*)(ws + 33554432);            // 196,608 B
  f16*   wlo  = (f16*)(ws + 33751040);            // 196,608 B
  float* bias3= (float*)(ws + 33947648);          // 1,536 B   (total ~33.9 MB, same as R5)

  k_wsplit<<<384, 256, 0, stream>>>(w_z, u_z, w_r, u_r, w, u, whi, wlo);
  k_bsum<<<3, HH, 0, stream>>>(b_wz, b_uz, b_wr, b_ur, b_w, b_u, bias3);
  k_copy_h0<<<8192, 256, 0, stream>>>(hidden, h);

  for (int t = 0; t < TT; t++) {
    k_biggemm<<<dim3(4, BB), 256, 0, stream>>>(A, h, b_ah, a32);
    k_gates<<<512, 256, 0, stream>>>(a32, h, whi, wlo, bias3);
  }
}